// Round 10
// baseline (137.157 us; speedup 1.0000x reference)
//
#include <hip/hip_runtime.h>

static constexpr int B_ = 256;
static constexpr int R_ = 1152;
static constexpr int C_ = 10;
static constexpr int O_ = 16;
static constexpr int I_ = 8;
static constexpr int SCO = C_ * O_;   // 160
static constexpr int K_ = R_ * I_;    // 9216
static constexpr int NB = 256;        // grid = CU count, 1 block/CU via LDS

typedef short bf16x8 __attribute__((ext_vector_type(8)));
typedef float f32x4  __attribute__((ext_vector_type(4)));

__device__ __forceinline__ unsigned short f2bf(float f) {
  union { float f; unsigned int u; } c; c.f = f;
  const unsigned int u = c.u;
  return (unsigned short)((u + 0x7fffu + ((u >> 16) & 1u)) >> 16);  // RNE
}
__device__ __forceinline__ float bf2f(unsigned short h) {
  union { unsigned int u; float f; } c; c.u = ((unsigned int)h) << 16; return c.f;
}

// bar[] layout (u32 indices; one 64B line per 16 u32):
#define FLAG_IDX(b)    ((b) * 16)                        // 256 lines: arrival
#define REQ_IDX(k)     (4096 + (k) * 16)                 // 8 lines: flush request
#define ACK_IDX(e)     (4224 + ((e) - 1) * 16)           // 4 lines: flush acks
#define GO_IDX(k)      (4352 + (k) * 16)                 // 8 lines: go broadcast
#define RESP_IDX(e, x) (4480 + (((e) - 1) * 8 + (x)) * 16) // 4x8: responder elect
#define NBLK_IDX(x)    (5120 + (x) * 16)                 // 8 lines: blocks/XCD

// ---------------------------------------------------------------------------
// Grid barrier v3 (r9-validated: body 94.7->79.8 us vs per-block RELEASE).
// ONE buffer_wbl2 per XCD per barrier: RELAXED arrival on own line -> block0
// detects 256 -> req broadcast -> first responder per real XCD (HW_REG_XCC_ID)
// does ONE RELEASE RMW on ack (wbl2 publishes every co-located block's stores)
// -> block0 waits ack == #occupied XCDs -> release-fence -> relaxed go.
// Consumers need no acquire: write-once buffers, first-touch reads
// (r7-validated). Guards degrade to wrong answer, never hang.
// ---------------------------------------------------------------------------
__device__ __forceinline__ void gsync(unsigned int* bar, unsigned int epoch,
                                      unsigned int myxcd) {
  __syncthreads();                     // drains all waves' stores into our L2
  const int bx = blockIdx.x, t = threadIdx.x;
  if (bx == 0) {
    if (t == 0)
      __hip_atomic_store(&bar[FLAG_IDX(0)], epoch,
                         __ATOMIC_RELAXED, __HIP_MEMORY_SCOPE_AGENT);
    if (t < 256) {
      int guard = 0;
      while (__hip_atomic_load(&bar[FLAG_IDX(t)],
                               __ATOMIC_RELAXED, __HIP_MEMORY_SCOPE_AGENT) < epoch) {
        __builtin_amdgcn_s_sleep(4);
        if (++guard > (1 << 18)) break;
      }
    }
    __syncthreads();                   // all 256 arrivals observed
    if (t == 0) {
      for (int k2 = 0; k2 < 8; ++k2)
        __hip_atomic_store(&bar[REQ_IDX(k2)], epoch,
                           __ATOMIC_RELAXED, __HIP_MEMORY_SCOPE_AGENT);
      const unsigned oldr = __hip_atomic_fetch_add(&bar[RESP_IDX(epoch, myxcd)], 1u,
                              __ATOMIC_RELAXED, __HIP_MEMORY_SCOPE_AGENT);
      if (oldr == 0)
        __hip_atomic_fetch_add(&bar[ACK_IDX(epoch)], 1u,
                               __ATOMIC_RELEASE, __HIP_MEMORY_SCOPE_AGENT); // wbl2
      unsigned nx = 0;
      for (int x2 = 0; x2 < 8; ++x2)
        nx += (__hip_atomic_load(&bar[NBLK_IDX(x2)],
                 __ATOMIC_RELAXED, __HIP_MEMORY_SCOPE_AGENT) > 0u) ? 1u : 0u;
      int guard = 0;
      while (__hip_atomic_load(&bar[ACK_IDX(epoch)],
                               __ATOMIC_RELAXED, __HIP_MEMORY_SCOPE_AGENT) < nx) {
        __builtin_amdgcn_s_sleep(4);
        if (++guard > (1 << 18)) break;
      }
      __builtin_amdgcn_fence(__ATOMIC_RELEASE, "agent");  // order obs -> go
      for (int k2 = 0; k2 < 8; ++k2)
        __hip_atomic_store(&bar[GO_IDX(k2)], epoch,
                           __ATOMIC_RELAXED, __HIP_MEMORY_SCOPE_AGENT);
    }
  } else {
    if (t == 0) {
      __hip_atomic_store(&bar[FLAG_IDX(bx)], epoch,
                         __ATOMIC_RELAXED, __HIP_MEMORY_SCOPE_AGENT);
      unsigned int* rq = &bar[REQ_IDX(bx & 7)];
      int guard = 0;
      while (__hip_atomic_load(rq, __ATOMIC_RELAXED,
                               __HIP_MEMORY_SCOPE_AGENT) < epoch) {
        __builtin_amdgcn_s_sleep(8);
        if (++guard > (1 << 17)) break;
      }
      const unsigned oldr = __hip_atomic_fetch_add(&bar[RESP_IDX(epoch, myxcd)], 1u,
                              __ATOMIC_RELAXED, __HIP_MEMORY_SCOPE_AGENT);
      if (oldr == 0)
        __hip_atomic_fetch_add(&bar[ACK_IDX(epoch)], 1u,
                               __ATOMIC_RELEASE, __HIP_MEMORY_SCOPE_AGENT); // wbl2
      unsigned int* g = &bar[GO_IDX(bx & 7)];
      guard = 0;
      while (__hip_atomic_load(g, __ATOMIC_RELAXED,
                               __HIP_MEMORY_SCOPE_AGENT) < epoch) {
        __builtin_amdgcn_s_sleep(8);
        if (++guard > (1 << 17)) break;
      }
    }
  }
  __syncthreads();
  asm volatile("" ::: "memory");       // compiler barrier only (r7-validated)
}

// ---------------------------------------------------------------------------
// gemm phase for it 1/2 (VERBATIM r9): 160 blocks, (4,5) XCD tiling; B = wraw
// scaled inline by e[c][r] (bit-identical to the materialized-wb2 path).
// ---------------------------------------------------------------------------
__device__ __forceinline__ void gemm_phase(
    int git, const unsigned short* __restrict__ xb,
    const unsigned short* __restrict__ wraw, const float* __restrict__ eX,
    float* __restrict__ Z, unsigned short* __restrict__ vbw,
    float* __restrict__ out, unsigned char* smem,
    int bx, int t, int w, int mrow, int quad) {
  float* sred = (float*)smem;                  // 8 x 272 floats
  float* szed = (float*)(smem + 16384);        // 10 floats
  float* e_lds = (float*)(smem + 20480);       // 1152 floats
  const int xcd = bx & 7, j = bx >> 3;         // j: 0..19
  const int mtile = (xcd >> 1) * 4 + j / 5;
  const int c = (xcd & 1) * 5 + j % 5;
  const int m0 = mtile * 16;
  for (int idx = t; idx < 1152; idx += 512) e_lds[idx] = eX[c * 1152 + idx];
  if (t < 10) szed[t] = atomicAdd(&Z[git * 10 + t], 0.0f);    // coherent read
  __syncthreads();
  const unsigned short* ap = xb + (size_t)(m0 + mrow) * K_ + w * 1152 + quad * 8;
  const unsigned short* bp = wraw + ((size_t)(w * 144 + quad) * C_ + c) * 128 + mrow * 8;
  f32x4 acc = {0.0f, 0.0f, 0.0f, 0.0f};
#pragma unroll 6
  for (int kk = 0; kk < 36; ++kk) {
    const bf16x8 a = *(const bf16x8*)(ap + kk * 32);
    const bf16x8 braw = *(const bf16x8*)(bp + (size_t)kk * 5120);
    const float ev = e_lds[w * 144 + kk * 4 + quad];          // broadcast
    bf16x8 b;
#pragma unroll
    for (int j8 = 0; j8 < 8; ++j8)
      b[j8] = (short)f2bf(bf2f((unsigned short)braw[j8]) * ev);
    acc = __builtin_amdgcn_mfma_f32_16x16x32_bf16(a, b, acc, 0, 0, 0);
  }
#pragma unroll
  for (int rg = 0; rg < 4; ++rg)
    sred[w * 272 + mrow * 17 + quad * 4 + rg] = acc[rg];
  __syncthreads();
  if (t < 256) {
    int m, n;
    if (git == 2) { m = t >> 4; n = t & 15; } else { n = t >> 4; m = t & 15; }
    const int e = n * 17 + m;
    const float ss = ((sred[0 * 272 + e] + sred[1 * 272 + e]) +
                      (sred[2 * 272 + e] + sred[3 * 272 + e])) +
                     ((sred[4 * 272 + e] + sred[5 * 272 + e]) +
                      (sred[6 * 272 + e] + sred[7 * 272 + e]));
    const float s = ss / szed[c];
    const float v = s * fabsf(s) / (1.0f + s * s);            // squash
    if (git == 2) out[(size_t)(m0 + m) * SCO + c * 16 + n] = v;
    else          vbw[(size_t)(c * 16 + n) * 256 + m0 + m] = f2bf(v);
  }
}

// ---------------------------------------------------------------------------
// pv phase (VERBATIM r9): 144 blocks x 8 r; emits bvec update + e[c][r] +
// Z partials only (scaled-W product deferred to next gemm).
// ---------------------------------------------------------------------------
__device__ __forceinline__ void pv_phase(
    int it, const unsigned short* __restrict__ xT,
    const unsigned short* __restrict__ vbr, const float* __restrict__ W,
    float* __restrict__ bvec, float* __restrict__ eOut, float* __restrict__ Z,
    unsigned char* smem, int bx, int t, int w, int mrow, int quad) {
  unsigned short* svb = (unsigned short*)smem;         // 80 KB staged vb
  float* sp = (float*)smem;                            // alias: P tiles
  float* sbs = (float*)(smem + 81920);                 // 80 floats
  const int seg = (bx & 7) * 18 + (bx >> 3);           // 0..143, XCD-swizzled
  const int r0 = seg * 8;
  bf16x8 afr[8];
  if (w < 4) {
    const unsigned short* ap = xT + (size_t)(seg * 64 + w * 16 + mrow) * 256 + quad * 8;
#pragma unroll
    for (int kk = 0; kk < 8; ++kk) afr[kk] = *(const bf16x8*)(ap + kk * 32);
  }
  {  // stage vb -> LDS, XOR-swizzled
    const char* src = (const char*)vbr;
    char* dst = (char*)svb;
#pragma unroll
    for (int i = 0; i < 10; ++i) {
      const int ci = i * 512 + t;
      const int lin = ci * 16;
      const int n = ci >> 5;
      *(bf16x8*)(dst + (lin ^ ((n & 7) << 4))) = *(const bf16x8*)(src + lin);
    }
  }
  __syncthreads();
  f32x4 acc[10];
  if (w < 4) {
#pragma unroll
    for (int c = 0; c < 10; ++c) acc[c] = (f32x4){0.0f, 0.0f, 0.0f, 0.0f};
#pragma unroll
    for (int c = 0; c < 10; ++c) {
      const int n = c * 16 + mrow;
      const int base = n * 512 + quad * 16;
#pragma unroll
      for (int kk = 0; kk < 8; ++kk) {
        const bf16x8 b = *(const bf16x8*)((const char*)svb +
                          ((base + kk * 64) ^ ((n & 7) << 4)));
        acc[c] = __builtin_amdgcn_mfma_f32_16x16x32_bf16(afr[kk], b, acc[c], 0, 0, 0);
      }
    }
  }
  __syncthreads();
  if (w < 4) {
#pragma unroll
    for (int c = 0; c < 10; ++c)
#pragma unroll
      for (int rg = 0; rg < 4; ++rg) {
        const int ml = w * 16 + quad * 4 + rg;         // m = rl*8+i, 0..63
        sp[(c * 8 + (ml >> 3)) * 128 + mrow * 8 + (ml & 7)] = acc[c][rg];
      }
  }
  __syncthreads();
  const int p16 = t >> 5, l32 = t & 31;
#pragma unroll
  for (int ch = 0; ch < 5; ++ch) {
    const int pair = ch * 16 + p16;                    // 0..79
    const int rl = pair / 10, c = pair - rl * 10;
    const float4 pv4 = *(const float4*)&sp[(c * 8 + rl) * 128 + l32 * 4];
    const float4 wv = *(const float4*)(W + (size_t)(r0 + rl) * 1280 + c * 128 + l32 * 4);
    float prod = wv.x * pv4.x + wv.y * pv4.y + wv.z * pv4.z + wv.w * pv4.w;
    prod += __shfl_xor(prod, 1);  prod += __shfl_xor(prod, 2);
    prod += __shfl_xor(prod, 4);  prod += __shfl_xor(prod, 8);
    prod += __shfl_xor(prod, 16);
    if (l32 == 0) sbs[rl * 10 + c] = prod;
  }
  __syncthreads();
  if (t < 80) {                                        // routing update + exp
    const int rl = t / 10, c = t - rl * 10;
    const int r = r0 + rl;
    float b = sbs[t] * (1.0f / 256.0f);
    if (it != 0) b += bvec[r * C_ + c];
    bvec[r * C_ + c] = b;
    const float e = expf(b);                           // |b| << 1: safe
    sbs[t] = e;
    eOut[c * 1152 + r] = e;
  }
  __syncthreads();
  if (t < 10) {
    float z = 0.0f;
#pragma unroll
    for (int rl = 0; rl < 8; ++rl) z += sbs[rl * 10 + t];
    atomicAdd(&Z[(it + 1) * 10 + t], z);
  }
}

// ===========================================================================
// mega: ONE plain launch, 256 blocks x 512 threads, 82.5 KB LDS (1 block/CU).
// Phase 0 (r10): [gemm0 on blocks 0..159, reading x/W fp32 with inline RNE
// conversion (bit-identical to the bf16 staging path; r5-validated)]
//             || [prep on blocks 160..255: W->wraw, x->xb+xT].
// Then pv0 -> gemm1 -> pv1 -> gemm2. 4 barriers (was 5): prep fully hidden
// under gemm0.
// ===========================================================================
__global__ __launch_bounds__(512, 1) void mega(
    const float* __restrict__ x, const float* __restrict__ W,
    float* __restrict__ out, unsigned int* __restrict__ bar,
    float* __restrict__ bvec, float* __restrict__ Z,
    float* __restrict__ eA, float* __restrict__ eB,
    unsigned short* __restrict__ xb, unsigned short* __restrict__ wraw,
    unsigned short* __restrict__ xT,
    unsigned short* __restrict__ vb0, unsigned short* __restrict__ vb1) {
  __shared__ __align__(16) unsigned char smem[82560];
  const int bx = blockIdx.x;
  const int t = threadIdx.x;
  const int lane = t & 63;
  const int w = __builtin_amdgcn_readfirstlane(t >> 6);   // 0..7
  const int mrow = lane & 15, quad = lane >> 4;

  unsigned int myxcd;
  asm volatile("s_getreg_b32 %0, hwreg(HW_REG_XCC_ID)" : "=s"(myxcd));
  myxcd &= 7u;
  if (t == 0)    // claim: blocks-per-XCD census (final before barrier-1 req)
    __hip_atomic_fetch_add(&bar[NBLK_IDX(myxcd)], 1u,
                           __ATOMIC_RELAXED, __HIP_MEMORY_SCOPE_AGENT);
  if (bx == 0 && t < 32) Z[t] = 0.0f;          // Z[10..29] accumulated by pv

  // ================= Phase 0: gemm0 (fp32 inline) || prep ==================
  if (bx < 160) {
    float* sred = (float*)smem;                // 8 x 272 floats
    const int xcd = bx & 7, j = bx >> 3;       // (4,5) XCD tiling (r8)
    const int mtile = (xcd >> 1) * 4 + j / 5;
    const int c = (xcd & 1) * 5 + j % 5;
    const int m0 = mtile * 16;
    const float* apf = x + (size_t)(m0 + mrow) * K_ + w * 1152 + quad * 8;
    const float* bpf = W + ((size_t)(w * 144 + quad) * C_ + c) * 128 + mrow * 8;
    f32x4 acc = {0.0f, 0.0f, 0.0f, 0.0f};
#pragma unroll 4
    for (int kk = 0; kk < 36; ++kk) {
      const float4 a0 = *(const float4*)(apf + kk * 32);
      const float4 a1 = *(const float4*)(apf + kk * 32 + 4);
      const float4 b0 = *(const float4*)(bpf + (size_t)kk * 5120);
      const float4 b1 = *(const float4*)(bpf + (size_t)kk * 5120 + 4);
      bf16x8 a, b;
      a[0] = (short)f2bf(a0.x); a[1] = (short)f2bf(a0.y);
      a[2] = (short)f2bf(a0.z); a[3] = (short)f2bf(a0.w);
      a[4] = (short)f2bf(a1.x); a[5] = (short)f2bf(a1.y);
      a[6] = (short)f2bf(a1.z); a[7] = (short)f2bf(a1.w);
      b[0] = (short)f2bf(b0.x); b[1] = (short)f2bf(b0.y);
      b[2] = (short)f2bf(b0.z); b[3] = (short)f2bf(b0.w);
      b[4] = (short)f2bf(b1.x); b[5] = (short)f2bf(b1.y);
      b[6] = (short)f2bf(b1.z); b[7] = (short)f2bf(b1.w);
      acc = __builtin_amdgcn_mfma_f32_16x16x32_bf16(a, b, acc, 0, 0, 0);
    }
#pragma unroll
    for (int rg = 0; rg < 4; ++rg)
      sred[w * 272 + mrow * 17 + quad * 4 + rg] = acc[rg];
    __syncthreads();
    if (t < 256) {
      const int n = t >> 4, m = t & 15;        // vb layout write
      const int e = n * 17 + m;
      const float ss = ((sred[0 * 272 + e] + sred[1 * 272 + e]) +
                        (sred[2 * 272 + e] + sred[3 * 272 + e])) +
                       ((sred[4 * 272 + e] + sred[5 * 272 + e]) +
                        (sred[6 * 272 + e] + sred[7 * 272 + e]));
      const float s = ss * (1.0f / 1152.0f);
      const float v = s * fabsf(s) / (1.0f + s * s);     // squash
      vb0[(size_t)(c * 16 + n) * 256 + m0 + m] = f2bf(v);
    }
  } else {
    // prep on 96 blocks: W -> wraw (3840 float4 each, exact), x -> xb + xT.
    const float4* wf = (const float4*)W;
    ushort4* wr = (ushort4*)wraw;
    for (int idx = t; idx < 3840; idx += 512) {
      const int j = (bx - 160) * 3840 + idx;
      const float4 v4 = wf[j];
      ushort4 r4;
      r4.x = f2bf(v4.x); r4.y = f2bf(v4.y); r4.z = f2bf(v4.z); r4.w = f2bf(v4.w);
      wr[j] = r4;
    }
    float* sx = (float*)smem;                  // 144 x 68 floats = 39168 B
    for (int u = bx - 160; u < 256; u += 96) { // 2-3 units of (64 b x 18 r)
      const int bq = u & 3, rseg = u >> 2;
      const int rbase = rseg * 18;
      __syncthreads();                         // sx reuse guard
      for (int idx = t; idx < 64 * 36; idx += 512) {
        const int b = idx / 36, f4 = idx - b * 36;
        const size_t off = (size_t)(bq * 64 + b) * K_ + rbase * I_ + f4 * 4;
        const float4 val = *(const float4*)(x + off);
        ushort4 o4;
        o4.x = f2bf(val.x); o4.y = f2bf(val.y); o4.z = f2bf(val.z); o4.w = f2bf(val.w);
        *(ushort4*)(xb + off) = o4;
        const int rr = f4 >> 1, i4 = (f4 & 1) * 4;
        sx[(rr * 8 + i4 + 0) * 68 + b] = val.x;
        sx[(rr * 8 + i4 + 1) * 68 + b] = val.y;
        sx[(rr * 8 + i4 + 2) * 68 + b] = val.z;
        sx[(rr * 8 + i4 + 3) * 68 + b] = val.w;
      }
      __syncthreads();
      for (int row = w * 18; row < w * 18 + 18; ++row)
        xT[(size_t)(rseg * 144 + row) * 256 + bq * 64 + lane] = f2bf(sx[row * 68 + lane]);
    }
  }
  gsync(bar, 1, myxcd);

  if (bx < 144) pv_phase(0, xT, vb0, W, bvec, eA, Z, smem, bx, t, w, mrow, quad);
  gsync(bar, 2, myxcd);

  if (bx < 160) gemm_phase(1, xb, wraw, eA, Z, vb1, out, smem, bx, t, w, mrow, quad);
  gsync(bar, 3, myxcd);

  if (bx < 144) pv_phase(1, xT, vb1, W, bvec, eB, Z, smem, bx, t, w, mrow, quad);
  gsync(bar, 4, myxcd);

  if (bx < 160) gemm_phase(2, xb, wraw, eB, Z, nullptr, out, smem, bx, t, w, mrow, quad);
}

extern "C" void kernel_launch(void* const* d_in, const int* in_sizes, int n_in,
                              void* d_out, int out_size, void* d_ws, size_t ws_size,
                              hipStream_t stream) {
  const float* x = (const float*)d_in[0];  // (B,R,I) fp32
  const float* W = (const float*)d_in[1];  // (R,C,O,I) fp32
  float* out = (float*)d_out;              // (B,C,O,1) fp32

  unsigned int* bar = (unsigned int*)d_ws;                 // 5376 u32 = 21504 B
  float* bvec = (float*)d_ws + 5376;                       // 11520
  float* Z    = bvec + R_ * C_;                            // 32
  float* eA   = Z + 32;                                    // 10 x 1152
  float* eB   = eA + C_ * R_;                              // 10 x 1152
  unsigned short* xb   = (unsigned short*)(eB + C_ * R_);  // B*K
  unsigned short* wraw = xb + (size_t)B_ * K_;             // R*C*O*I
  unsigned short* xT   = wraw + (size_t)R_ * C_ * O_ * I_; // R*8*256
  unsigned short* vb0  = xT + (size_t)R_ * 8 * 256;        // 160*256
  unsigned short* vb1  = vb0 + (size_t)160 * 256;          // 160*256

  hipMemsetAsync(bar, 0, 21504, stream);                   // capture-safe
  mega<<<NB, 512, 0, stream>>>(x, W, out, bar, bvec, Z, eA, eB,
                               xb, wraw, xT, vb0, vb1);
}